// Round 1
// baseline (137.026 us; speedup 1.0000x reference)
//
#include <hip/hip_runtime.h>
#include <hip/hip_bf16.h>

#define EDIM 256
#define NROWS 8192

typedef __attribute__((ext_vector_type(8))) short bf16x8;
typedef __attribute__((ext_vector_type(4))) float f32x4;

// ---------------------------------------------------------------------------
// Kernel 1: normalize rows of W = [v0; v1] (L2 over E, scale sqrt(10)),
// emit bf16 W row-major [8192][256], zero S/pos accumulators.
// Input layout: view[b][e][n], flat = b*16384 + e*64 + n.  Row r = view*4096 + b*64 + n.
// ---------------------------------------------------------------------------
__global__ void detcon_normalize(const float* __restrict__ v0,
                                 const float* __restrict__ v1,
                                 __hip_bfloat16* __restrict__ Wb,
                                 float* __restrict__ S,
                                 float* __restrict__ pos) {
  const int r = blockIdx.x;   // 0..8191
  const int e = threadIdx.x;  // 0..255
  const float* src = (r < 4096) ? v0 : v1;
  const int rr = r & 4095;
  const int b = rr >> 6;
  const int n = rr & 63;
  const float x = src[b * (EDIM * 64) + e * 64 + n];
  float sq = x * x;
#pragma unroll
  for (int m = 32; m >= 1; m >>= 1) sq += __shfl_xor(sq, m, 64);
  __shared__ float wsum[4];
  const int wid = threadIdx.x >> 6;
  const int lane = threadIdx.x & 63;
  if (lane == 0) wsum[wid] = sq;
  __syncthreads();
  const float total = wsum[0] + wsum[1] + wsum[2] + wsum[3];
  // x / (||x|| + 1e-8) / sqrt(0.1)
  const float scale = 3.16227766016838f / (sqrtf(total) + 1e-8f);
  Wb[r * EDIM + e] = __float2bfloat16(x * scale);
  if (threadIdx.x == 0) { S[r] = 0.0f; pos[r] = 0.0f; }
}

// ---------------------------------------------------------------------------
// Kernel 2: fused Gram + online sum-of-exp.
// Grid: (4 col-blocks, 128 row-blocks). Block: 256 thr (4 waves), 64 rows.
// A-frags in registers (K=256 fully), B tiles (128 cols x 256 K) streamed
// through 64 KB LDS with XOR swizzle ((col&7)<<4) applied on the global
// SOURCE address at staging and on the ds_read address (involution).
// Each wave owns a distinct 32-col strip -> no duplicated LDS reads.
// ---------------------------------------------------------------------------
__global__ __launch_bounds__(256, 2) void detcon_gram_lse(
    const __hip_bfloat16* __restrict__ Wbh,
    float* __restrict__ S,
    float* __restrict__ pos) {
  __shared__ __align__(16) unsigned char b_lds[65536];
  const int tid = threadIdx.x;
  const int lane = tid & 63;
  const int wid = tid >> 6;
  const int rowbase = blockIdx.y * 64;
  const int colblock = blockIdx.x * 2048;
  const char* Wbytes = (const char*)Wbh;
  const unsigned short* W = (const unsigned short*)Wbh;

  // A fragments: a[m][kb], lane holds A[row = m*16 + (lane&15)][k = kb*32 + (lane>>4)*8 + i]
  bf16x8 a[4][8];
#pragma unroll
  for (int m = 0; m < 4; ++m) {
    const int row = rowbase + m * 16 + (lane & 15);
#pragma unroll
    for (int kb = 0; kb < 8; ++kb) {
      const int k0 = kb * 32 + (lane >> 4) * 8;
      a[m][kb] = *(const bf16x8*)(W + row * EDIM + k0);
    }
  }

  f32x4 acc[4][2];
  float s[4][4];
#pragma unroll
  for (int m = 0; m < 4; ++m) {
#pragma unroll
    for (int n = 0; n < 2; ++n) acc[m][n] = (f32x4){0.f, 0.f, 0.f, 0.f};
#pragma unroll
    for (int j = 0; j < 4; ++j) s[m][j] = 0.f;
  }

  for (int it = 0; it < 16; ++it) {
    const int colbase = colblock + it * 128;
    // ---- stage B tile: 128 cols x 512 B, source-swizzled ----
#pragma unroll 4
    for (int i = 0; i < 16; ++i) {
      const int q = (i * 256 + tid) * 16;     // linear LDS byte offset
      const int c = q >> 9;                   // local col
      const int inner = q & 511;              // byte within the col row
      const int srcoff = ((colbase + c) << 9) + (inner ^ ((c & 7) << 4));
      *(uint4*)(b_lds + q) = *(const uint4*)(Wbytes + srcoff);
    }
    __syncthreads();

    // ---- compute 64 x 128 G tile ----
#pragma unroll
    for (int kb = 0; kb < 8; ++kb) {
      bf16x8 bfrag[2];
#pragma unroll
      for (int n = 0; n < 2; ++n) {
        const int c_local = wid * 32 + n * 16 + (lane & 15);
        const int koff = kb * 64 + (lane >> 4) * 16;  // bytes
        const int addr = (c_local << 9) + (koff ^ ((c_local & 7) << 4));
        bfrag[n] = *(const bf16x8*)(b_lds + addr);
      }
#pragma unroll
      for (int m = 0; m < 4; ++m) {
#pragma unroll
        for (int n = 0; n < 2; ++n)
          acc[m][n] = __builtin_amdgcn_mfma_f32_16x16x32_bf16(
              a[m][kb], bfrag[n], acc[m][n], 0, 0, 0);
      }
    }
    __syncthreads();

    // ---- epilogue: exp-accumulate (skip diagonal), capture positive ----
#pragma unroll
    for (int m = 0; m < 4; ++m) {
#pragma unroll
      for (int n = 0; n < 2; ++n) {
#pragma unroll
        for (int j = 0; j < 4; ++j) {
          const float g = acc[m][n][j];
          const int grow = rowbase + m * 16 + (lane >> 4) * 4 + j;
          const int gcol = colbase + wid * 32 + n * 16 + (lane & 15);
          const float e = (gcol == grow) ? 0.f : __expf(g);
          s[m][j] += e;
          if (gcol == ((grow + 4096) & 8191)) pos[grow] = g;  // unique writer
        }
        acc[m][n] = (f32x4){0.f, 0.f, 0.f, 0.f};
      }
    }
  }

  // ---- reduce per-row sums across the 16 lanes sharing a row ----
#pragma unroll
  for (int m = 0; m < 4; ++m) {
#pragma unroll
    for (int j = 0; j < 4; ++j) {
      float v = s[m][j];
      v += __shfl_xor(v, 1, 64);
      v += __shfl_xor(v, 2, 64);
      v += __shfl_xor(v, 4, 64);
      v += __shfl_xor(v, 8, 64);
      if ((lane & 15) == 0)
        atomicAdd(&S[rowbase + m * 16 + (lane >> 4) * 4 + j], v);
    }
  }
}

// ---------------------------------------------------------------------------
// Kernel 3: nll_r = log(S_r) - pos_r; out = mean.
// ---------------------------------------------------------------------------
__global__ void detcon_finalize(const float* __restrict__ S,
                                const float* __restrict__ pos,
                                float* __restrict__ out) {
  float local = 0.f;
  for (int r = threadIdx.x; r < NROWS; r += 256)
    local += logf(S[r]) - pos[r];
#pragma unroll
  for (int m = 32; m >= 1; m >>= 1) local += __shfl_xor(local, m, 64);
  __shared__ float wsum[4];
  const int wid = threadIdx.x >> 6;
  const int lane = threadIdx.x & 63;
  if (lane == 0) wsum[wid] = local;
  __syncthreads();
  if (threadIdx.x == 0)
    out[0] = (wsum[0] + wsum[1] + wsum[2] + wsum[3]) * (1.0f / (float)NROWS);
}

extern "C" void kernel_launch(void* const* d_in, const int* in_sizes, int n_in,
                              void* d_out, int out_size, void* d_ws, size_t ws_size,
                              hipStream_t stream) {
  const float* v0 = (const float*)d_in[0];
  const float* v1 = (const float*)d_in[1];
  float* out = (float*)d_out;

  // ws layout: Wb bf16[8192][256] (4 MB) | S f32[8192] | pos f32[8192]
  __hip_bfloat16* Wb = (__hip_bfloat16*)d_ws;
  float* S = (float*)((char*)d_ws + (size_t)NROWS * EDIM * 2);
  float* pos = S + NROWS;

  detcon_normalize<<<NROWS, 256, 0, stream>>>(v0, v1, Wb, S, pos);
  detcon_gram_lse<<<dim3(4, 128), 256, 0, stream>>>(Wb, S, pos);
  detcon_finalize<<<1, 256, 0, stream>>>(S, pos, out);
}

// Round 2
// 113.371 us; speedup vs baseline: 1.2086x; 1.2086x over previous
//
#include <hip/hip_runtime.h>
#include <hip/hip_bf16.h>

#define EDIM 256
#define NROWS 8192

typedef __attribute__((ext_vector_type(8))) short bf16x8;
typedef __attribute__((ext_vector_type(4))) float f32x4;

__device__ __forceinline__ unsigned short f2bf(float f) {
  unsigned int u = __float_as_uint(f);
  unsigned int r = (u + 0x7fffu + ((u >> 16) & 1u)) >> 16;  // RNE
  return (unsigned short)r;
}

__device__ __forceinline__ void gload_lds16(const void* g, void* l) {
  __builtin_amdgcn_global_load_lds(
      (const __attribute__((address_space(1))) unsigned int*)g,
      (__attribute__((address_space(3))) unsigned int*)l, 16, 0, 0);
}

// ---------------------------------------------------------------------------
// Kernel 1: normalize + transpose -> bf16 W[8192][256].
// Block = (view, b, n-half): 256 blocks, 256 threads. Coalesced f4 loads,
// LDS transpose, coalesced bf16x8 row writes.
// ---------------------------------------------------------------------------
__global__ __launch_bounds__(256) void detcon_normalize(
    const float* __restrict__ v0, const float* __restrict__ v1,
    __hip_bfloat16* __restrict__ Wb) {
  __shared__ float Xs[EDIM][32];   // [e][n_local], 32 KB
  __shared__ float part[4][32];
  __shared__ float scale_s[32];
  const int t = threadIdx.x;
  const int bid = blockIdx.x;              // 0..255
  const int view = bid >> 7;               // 0/1
  const int b = (bid >> 1) & 63;
  const int nh = (bid & 1) * 32;           // n offset
  const float* src = (view ? v1 : v0) + (size_t)b * (EDIM * 64);

  const int n4 = t & 7;                    // n_local group (x4)
  const int eg = t >> 3;                   // 0..31
  float4 ss = {0.f, 0.f, 0.f, 0.f};
#pragma unroll
  for (int i = 0; i < 8; ++i) {
    const int e = i * 32 + eg;
    float4 x = *(const float4*)(src + e * 64 + nh + n4 * 4);
    *(float4*)(&Xs[e][n4 * 4]) = x;
    ss.x += x.x * x.x; ss.y += x.y * x.y; ss.z += x.z * x.z; ss.w += x.w * x.w;
  }
  // reduce over eg within wave (lane>>3 in 0..7): xor 8,16,32
#pragma unroll
  for (int m = 8; m <= 32; m <<= 1) {
    ss.x += __shfl_xor(ss.x, m, 64);
    ss.y += __shfl_xor(ss.y, m, 64);
    ss.z += __shfl_xor(ss.z, m, 64);
    ss.w += __shfl_xor(ss.w, m, 64);
  }
  if ((t & 63) < 8) *(float4*)(&part[t >> 6][(t & 7) * 4]) = ss;
  __syncthreads();
  if (t < 32) {
    const float total = part[0][t] + part[1][t] + part[2][t] + part[3][t];
    scale_s[t] = 3.16227766016838f / (sqrtf(total) + 1e-8f);
  }
  __syncthreads();

  // writeout: thread t -> row n = t>>3 (local), e-range (t&7)*32 .. +32
  const int nl = t >> 3;
  const int e0 = (t & 7) * 32;
  const float sc = scale_s[nl];
  const size_t r = (size_t)view * 4096 + (size_t)b * 64 + nh + nl;
  __hip_bfloat16* dst = Wb + r * EDIM;
#pragma unroll
  for (int j = 0; j < 4; ++j) {
    bf16x8 o;
#pragma unroll
    for (int u = 0; u < 8; ++u)
      o[u] = (short)f2bf(Xs[e0 + j * 8 + u][nl] * sc);
    *(bf16x8*)(dst + e0 + j * 8) = o;
  }
}

// ---------------------------------------------------------------------------
// Kernel 2: fused Gram + sum-of-exp (incl. diagonal; subtracted in finalize).
// Grid (4 col-blocks, 64 row-blocks), 512 thr = 8 waves (2 wave-rows x 4
// wave-cols). Wave: 64 rows (A full-K in regs) x 16 cols per iter.
// B tiles 64 cols x 512 B double-buffered, global_load_lds w16, source-side
// XOR swizzle ((c&7)<<4). T3 minimum-2-phase: stage next, compute cur, one
// __syncthreads per iter (its vmcnt(0) is ~free: loads issued a phase ago).
// ---------------------------------------------------------------------------
__global__ __launch_bounds__(512, 2) void detcon_gram_lse(
    const __hip_bfloat16* __restrict__ Wbh, float* __restrict__ S) {
  __shared__ __align__(16) unsigned char b_lds[2][32768];
  const int tid = threadIdx.x;
  const int lane = tid & 63;
  const int wid = tid >> 6;           // 0..7
  const int wrow = wid >> 2;          // 0..1
  const int wcol = wid & 3;           // 0..3
  const int rowbase = blockIdx.y * 128 + wrow * 64;
  const int colblock = blockIdx.x * 2048;
  const unsigned short* W = (const unsigned short*)Wbh;
  const char* Wbytes = (const char*)Wbh;

  // A fragments (full K): lane holds A[rowbase+m*16+(lane&15)][kb*32+(lane>>4)*8 ..+8]
  bf16x8 a[4][8];
#pragma unroll
  for (int m = 0; m < 4; ++m) {
    const size_t row = rowbase + m * 16 + (lane & 15);
#pragma unroll
    for (int kb = 0; kb < 8; ++kb)
      a[m][kb] = *(const bf16x8*)(W + row * EDIM + kb * 32 + (lane >> 4) * 8);
  }

  f32x4 acc[4];
  float s[4][4];
#pragma unroll
  for (int m = 0; m < 4; ++m) {
    acc[m] = (f32x4){0.f, 0.f, 0.f, 0.f};
#pragma unroll
    for (int j = 0; j < 4; ++j) s[m][j] = 0.f;
  }

  const int stage_cl = wid * 8 + (lane >> 5);        // + i*2
  const int stage_inner = (lane & 31) * 16;

#define STAGE(BUF, COLBASE)                                                    \
  {                                                                            \
    _Pragma("unroll")                                                          \
    for (int i = 0; i < 4; ++i) {                                              \
      const int cl = stage_cl + i * 2;                                         \
      const char* g = Wbytes + ((size_t)((COLBASE) + cl) << 9) +               \
                      (stage_inner ^ ((cl & 7) << 4));                         \
      gload_lds16(g, &b_lds[BUF][wid * 4096 + i * 1024]);                      \
    }                                                                          \
  }

  STAGE(0, colblock);
  __syncthreads();

  int cur = 0;
  for (int it = 0; it < 32; ++it) {
    if (it + 1 < 32) STAGE(cur ^ 1, colblock + (it + 1) * 64);

    const int cl = wcol * 16 + (lane & 15);
    const unsigned char* bbase = &b_lds[cur][cl << 9];
    const int csw = (cl & 7) << 4;
#pragma unroll
    for (int kb = 0; kb < 8; ++kb) {
      const int koff = kb * 64 + (lane >> 4) * 16;
      bf16x8 bfrag = *(const bf16x8*)(bbase + (koff ^ csw));
#pragma unroll
      for (int m = 0; m < 4; ++m)
        acc[m] = __builtin_amdgcn_mfma_f32_16x16x32_bf16(a[m][kb], bfrag,
                                                         acc[m], 0, 0, 0);
    }
    // epilogue: unconditional exp-accumulate (diag handled in finalize)
#pragma unroll
    for (int m = 0; m < 4; ++m) {
#pragma unroll
      for (int j = 0; j < 4; ++j) s[m][j] += __expf(acc[m][j]);
      acc[m] = (f32x4){0.f, 0.f, 0.f, 0.f};
    }
    __syncthreads();   // drains stage(it+1) loads (issued a full phase ago) + barrier
    cur ^= 1;
  }

  // reduce row sums across the 16 col-lanes, one atomic per row
#pragma unroll
  for (int m = 0; m < 4; ++m) {
#pragma unroll
    for (int j = 0; j < 4; ++j) {
      float v = s[m][j];
      v += __shfl_xor(v, 1, 64);
      v += __shfl_xor(v, 2, 64);
      v += __shfl_xor(v, 4, 64);
      v += __shfl_xor(v, 8, 64);
      if ((lane & 15) == 0)
        atomicAdd(&S[rowbase + m * 16 + (lane >> 4) * 4 + j], v);
    }
  }
#undef STAGE
}

// ---------------------------------------------------------------------------
// Kernel 3: per row r: selfdot = W[r].W[r], posdot = W[r].W[(r+4096)%8192];
// nll = log(S[r] - exp(selfdot)) - posdot; out = mean (atomicAdd, out zeroed).
// ---------------------------------------------------------------------------
__global__ __launch_bounds__(256) void detcon_finalize(
    const __hip_bfloat16* __restrict__ Wbh, const float* __restrict__ S,
    float* __restrict__ out) {
  const int t = threadIdx.x;
  const int r = blockIdx.x * 256 + t;
  const int p = (r + 4096) & (NROWS - 1);
  const uint4* Wr = (const uint4*)((const char*)Wbh + (size_t)r * 512);
  const uint4* Wp = (const uint4*)((const char*)Wbh + (size_t)p * 512);
  float sd = 0.f, pd = 0.f;
#pragma unroll 8
  for (int i = 0; i < 32; ++i) {
    uint4 x = Wr[i], y = Wp[i];
    const unsigned int* xd = (const unsigned int*)&x;
    const unsigned int* yd = (const unsigned int*)&y;
#pragma unroll
    for (int k = 0; k < 4; ++k) {
      float xl = __uint_as_float(xd[k] << 16);
      float xh = __uint_as_float(xd[k] & 0xffff0000u);
      float yl = __uint_as_float(yd[k] << 16);
      float yh = __uint_as_float(yd[k] & 0xffff0000u);
      sd += xl * xl + xh * xh;
      pd += xl * yl + xh * yh;
    }
  }
  float nll = logf(S[r] - __expf(sd)) - pd;
#pragma unroll
  for (int m = 32; m >= 1; m >>= 1) nll += __shfl_xor(nll, m, 64);
  __shared__ float wsum[4];
  if ((t & 63) == 0) wsum[t >> 6] = nll;
  __syncthreads();
  if (t == 0)
    atomicAdd(out, (wsum[0] + wsum[1] + wsum[2] + wsum[3]) * (1.0f / NROWS));
}

extern "C" void kernel_launch(void* const* d_in, const int* in_sizes, int n_in,
                              void* d_out, int out_size, void* d_ws, size_t ws_size,
                              hipStream_t stream) {
  const float* v0 = (const float*)d_in[0];
  const float* v1 = (const float*)d_in[1];
  float* out = (float*)d_out;

  __hip_bfloat16* Wb = (__hip_bfloat16*)d_ws;
  float* S = (float*)((char*)d_ws + (size_t)NROWS * EDIM * 2);

  hipMemsetAsync(S, 0, NROWS * sizeof(float), stream);
  hipMemsetAsync(d_out, 0, sizeof(float), stream);
  detcon_normalize<<<256, 256, 0, stream>>>(v0, v1, Wb);
  detcon_gram_lse<<<dim3(4, 64), 512, 0, stream>>>(Wb, S);
  detcon_finalize<<<NROWS / 256, 256, 0, stream>>>(Wb, S, out);
}